// Round 1
// baseline (699.815 us; speedup 1.0000x reference)
//
#include <hip/hip_runtime.h>

// Cosine similarity of each pixel's C=128 vector with its 8 neighbors (3x3,
// zero-padded), minus 1.  Identity: out = dot(xn, boxsum3x3(xn)) - 1.
// Single pass over the 512 MiB input -> HBM-read-bound (~95 us floor).
//
// R1 changes vs 700us baseline (latency-bound theory):
//  - one-row-ahead global prefetch into registers (issue y+1 before using y)
//  - double-buffered xrow + raw s_barrier with lgkmcnt-only drain: 1 barrier
//    per row, prefetch loads stay in flight across the barrier (no vmcnt(0))
//  - rsqrtf instead of precise sqrt+div in the normalize

#define HH 1024
#define WW 1024
#define C4 32          // float4 chunks per pixel (128 channels)
#define SOUT 64        // output columns per strip
#define SHALO (SOUT + 2)
#define RROWS 32       // output rows per block
#define NT 512
#define NSTAGE ((SHALO * C4 + NT - 1) / NT)   // 5 (last partial)
#define OWN ((SOUT * C4) / NT)                // 4 owned (x,chunk) per thread

__device__ __forceinline__ float dot4(float4 a, float4 b) {
    return fmaf(a.x, b.x, fmaf(a.y, b.y, fmaf(a.z, b.z, a.w * b.w)));
}

__device__ __forceinline__ void stage_row(const float4* __restrict__ in,
                                          int y, int x0, int t, bool need,
                                          float4 (&v)[NSTAGE]) {
#pragma unroll
    for (int i = 0; i < NSTAGE; ++i) {
        const int idx = t + i * NT;          // (x_in, chunk) flat
        float4 val = make_float4(0.f, 0.f, 0.f, 0.f);
        const bool inR = (i < NSTAGE - 1) || (idx < SHALO * C4);
        if (inR) {
            const int gx = x0 - 1 + (idx >> 5);
            if (need && gx >= 0 && gx < WW) {
                val = in[(size_t)(y * WW + gx) * C4 + (idx & 31)];
            }
        }
        v[i] = val;
    }
}

__global__ __launch_bounds__(NT, 4)
void cos_sim_kernel(const float4* __restrict__ in, float* __restrict__ out) {
    // Two row buffers (ping-pong): write buf, barrier, read buf; next row
    // writes buf^1 so no read->write barrier is needed.  66 KB LDS -> still
    // 2 blocks/CU (VGPR-capped anyway).
    __shared__ float4 xrow[2][SHALO * C4];

    const int t   = threadIdx.x;
    const int c4  = t & 31;       // channel chunk within pixel
    const int xo0 = t >> 5;       // base owned output col (0..15), +16*i
    const int x0  = blockIdx.x * SOUT;   // strip base (output cols)
    const int r0  = blockIdx.y * RROWS;  // row-chunk base
    const int ylast = r0 + RROWS;

    // Rolling per-owned-pixel state: H of previous input row, xn of previous
    // input row, and the partial accumulator for output row (y-1).
    float4 Hprev[OWN], XNprev[OWN];
    float  accP[OWN];
#pragma unroll
    for (int i = 0; i < OWN; ++i) {
        Hprev[i]  = make_float4(0.f, 0.f, 0.f, 0.f);
        XNprev[i] = make_float4(0.f, 0.f, 0.f, 0.f);
        accP[i]   = 0.f;
    }

    float4 vA[NSTAGE], vB[NSTAGE];
    stage_row(in, r0 - 1, x0, t, (r0 - 1 >= 0), vA);

    int buf = 0;
    for (int y = r0 - 1; y <= ylast; ++y) {
        // ---- issue next row's loads NOW; waited on at the vA=vB copy at
        //      iteration end -> latency hidden under normalize+compute ----
        const int yn = y + 1;
        stage_row(in, yn, x0, t,
                  (yn >= 0) && (yn < HH) && (yn <= ylast), vB);

        // ---- normalize vA: per-pixel norm via 32-lane xor reduce -> LDS ----
#pragma unroll
        for (int i = 0; i < NSTAGE; ++i) {
            const int idx = t + i * NT;
            float s = dot4(vA[i], vA[i]);
            s += __shfl_xor(s, 1);
            s += __shfl_xor(s, 2);
            s += __shfl_xor(s, 4);
            s += __shfl_xor(s, 8);
            s += __shfl_xor(s, 16);
            // rsqrtf(max(s,1e-16)) == 1/max(sqrt(s),1e-8) (same clamp), but
            // ~5x fewer VALU ops than precise sqrt + precise divide.
            const float inv = rsqrtf(fmaxf(s, 1e-16f));
            const bool inR = (i < NSTAGE - 1) || (idx < SHALO * C4);
            if (inR) {
                float4 w;
                w.x = vA[i].x * inv; w.y = vA[i].y * inv;
                w.z = vA[i].z * inv; w.w = vA[i].w * inv;
                xrow[buf][idx] = w;
            }
        }

        // LDS-writes-only drain + raw barrier: prefetch (vmcnt) stays in
        // flight across the barrier, unlike __syncthreads' vmcnt(0) drain.
        asm volatile("s_waitcnt lgkmcnt(0)" ::: "memory");
        __builtin_amdgcn_s_barrier();

        // ---- compute: H_y in registers, pair with rolling xn/H state ----
#pragma unroll
        for (int i = 0; i < OWN; ++i) {
            const int xo = xo0 + 16 * i;                     // output col
            const float4 a = xrow[buf][(xo    ) * C4 + c4];  // x-1
            const float4 b = xrow[buf][(xo + 1) * C4 + c4];  // x   (center)
            const float4 r = xrow[buf][(xo + 2) * C4 + c4];  // x+1
            float4 Hc;
            Hc.x = a.x + b.x + r.x; Hc.y = a.y + b.y + r.y;
            Hc.z = a.z + b.z + r.z; Hc.w = a.w + b.w + r.w;

            // out(y-1) completes: += dot(xn_{y-1}, H_y)
            float fin = accP[i] + dot4(XNprev[i], Hc);
            // out(y) partial: dot(xn_y, H_{y-1}) + dot(xn_y, H_y)
            accP[i]   = dot4(b, Hprev[i]) + dot4(b, Hc);
            XNprev[i] = b;
            Hprev[i]  = Hc;

            if (y > r0) {   // uniform branch: finalize row y-1 (in range)
                fin += __shfl_xor(fin, 1);
                fin += __shfl_xor(fin, 2);
                fin += __shfl_xor(fin, 4);
                fin += __shfl_xor(fin, 8);
                fin += __shfl_xor(fin, 16);
                if (c4 == 0) {
                    out[(size_t)(y - 1) * WW + x0 + xo] = fin - 1.0f;
                }
            }
        }

        buf ^= 1;
        // The copy is where the compiler waits on vB's loads -> the wait
        // lands a full iteration after issue.
#pragma unroll
        for (int i = 0; i < NSTAGE; ++i) vA[i] = vB[i];
    }
}

extern "C" void kernel_launch(void* const* d_in, const int* in_sizes, int n_in,
                              void* d_out, int out_size, void* d_ws, size_t ws_size,
                              hipStream_t stream) {
    const float4* in = (const float4*)d_in[0];
    float* out = (float*)d_out;
    dim3 grid(WW / SOUT, HH / RROWS);   // 16 x 32 = 512 blocks
    cos_sim_kernel<<<grid, NT, 0, stream>>>(in, out);
}